// Round 11
// baseline (165.224 us; speedup 1.0000x reference)
//
#include <hip/hip_runtime.h>
#include <hip/hip_bf16.h>

#define MB_ROWS  8192            // 16 * 512
#define N_LINES  12
#define SCALE    (0.01f / 512.0f)
#define FL_CONST 170.0f          // PROBE_CTS * FL_RATIO * SA_ADJ * SA_THETA

// 8-byte (4B-aligned) load carrying both x-taps of one source row.
struct __attribute__((packed, aligned(4))) F2 { float x, y; };

struct Coord {
    int oA, oB;
    float w00, w10, w01, w11;   // (y0,x0) (y0,x1) (y1,x0) (y1,x1)
    bool edge;
};

__device__ __forceinline__ Coord mk_coord(int s, float gyr, float cs, float sn) {
    Coord cd;
    const float gx = (2.0f * (float)s + 1.0f) * (1.0f / 512.0f) - 1.0f;
    const float x_in = cs * gx - sn * gyr;
    const float y_in = sn * gx + cs * gyr;
    float ix = ((x_in + 1.0f) * 512.0f - 1.0f) * 0.5f;
    float iy = ((y_in + 1.0f) * 512.0f - 1.0f) * 0.5f;
    ix = fminf(fmaxf(ix, 0.0f), 511.0f);
    iy = fminf(fmaxf(iy, 0.0f), 511.0f);
    const float x0f = floorf(ix);
    const float y0f = floorf(iy);
    const float wx = ix - x0f;
    const float wy = iy - y0f;
    const int x0 = (int)x0f;
    const int y0 = (int)y0f;
    const int y1 = min(y0 + 1, 511);
    cd.edge = (x0 >= 511);
    const int xL = cd.edge ? 510 : x0;
    cd.w00 = (1.0f - wx) * (1.0f - wy);
    cd.w10 = wx * (1.0f - wy);
    cd.w01 = (1.0f - wx) * wy;
    cd.w11 = wx * wy;
    cd.oA = y0 * 512 + xL;
    cd.oB = y1 * 512 + xL;
    return cd;
}

__device__ __forceinline__ void issue_loads(const float* __restrict__ base,
                                            size_t estride, const Coord& cd,
                                            F2* A, F2* B) {
#pragma unroll
    for (int e = 0; e < 5; ++e) {
        const float* p = base + (size_t)e * estride;
        A[e] = *(const F2*)(p + cd.oA);
        B[e] = *(const F2*)(p + cd.oB);
    }
}

// Block = 8 output rows (one channel) x 512 samples. 8 waves; wave w owns
// segment w (64 samples) of all 8 rows as 8 chunks of 8 samples. Lane =
// (r = lane>>3, j = lane&7): 8x8 output patch per gather instruction.
// Segmented 8-wide shfl scan with in-register carry; zero LDS/barriers in
// the main loop; segments stitched via exp(-(P+q)) = exp(-P)*exp(-q).
// R11: fully-unrolled k-loop with SOFTWARE PIPELINE - chunk k+1's 10 loads
// (and address math) issue before chunk k's scan/exp chain, so the scan
// chain overlaps the next chunk's memory latency instead of serializing.
__global__ __launch_bounds__(512) void fused_fl_kernel(
    const float* __restrict__ xp,       // (5, 16, 512, 512)
    const float* __restrict__ attCS,    // (5,)
    const float* __restrict__ dfl,      // (12,)
    const float* __restrict__ theta_p,  // (1,)
    const int*   __restrict__ lidx,     // (12,)
    float*       __restrict__ out)      // fl_sig (12*8192) ++ transmission (8192)
{
    const int bid = blockIdx.x;
    const int t   = bid >> 3;
    const int c   = (bid & 7) + 8 * (t >> 6);   // channel, XCD-affine
    const int g   = t & 63;
    const int irow0 = g << 3;

    const int tid  = threadIdx.x;
    const int lane = tid & 63;
    const int w    = tid >> 6;   // segment 0..7
    const int j    = lane & 7;   // sample within chunk
    const int r    = lane >> 3;  // row within group

    const float theta = theta_p[0];
    const float cs = cosf(theta);
    const float sn = sinf(theta);

    const float gyr = (2.0f * (float)(irow0 + r) + 1.0f) * (1.0f / 512.0f) - 1.0f;

    const size_t estride = (size_t)16 * 512 * 512;
    const float* base = xp + (size_t)c * (512 * 512);

    const float a0 = attCS[0], a1 = attCS[1], a2 = attCS[2], a3 = attCS[3], a4 = attCS[4];

    __shared__ float s_seg[8][8][6];   // [seg][row][A, S0..S4] = 1536 B

    float se0 = 0.f, se1 = 0.f, se2 = 0.f, se3 = 0.f, se4 = 0.f;
    float carry = 0.f;

    const int sbase = (w << 6) + j;

    // ---- software-pipelined, fully-unrolled chunk loop ----
    Coord cd = mk_coord(sbase, gyr, cs, sn);
    F2 A[5], B[5];
    issue_loads(base, estride, cd, A, B);

#pragma unroll
    for (int k = 0; k < 8; ++k) {
        // prefetch chunk k+1 (addresses + loads) BEFORE consuming chunk k
        Coord cdn;
        F2 An[5], Bn[5];
        if (k < 7) {
            cdn = mk_coord(sbase + ((k + 1) << 3), gyr, cs, sn);
            issue_loads(base, estride, cdn, An, Bn);
        }

        // interpolate chunk k
        float cv[5];
#pragma unroll
        for (int e = 0; e < 5; ++e) {
            const float vA0 = cd.edge ? A[e].y : A[e].x;
            const float vB0 = cd.edge ? B[e].y : B[e].x;
            float acc = cd.w00 * vA0;
            acc = fmaf(cd.w10, A[e].y, acc);
            acc = fmaf(cd.w01, vB0, acc);
            acc = fmaf(cd.w11, B[e].y, acc);
            cv[e] = acc;
        }

        float lac = a0 * cv[0];
        lac = fmaf(a1, cv[1], lac);
        lac = fmaf(a2, cv[2], lac);
        lac = fmaf(a3, cv[3], lac);
        lac = fmaf(a4, cv[4], lac);

        // segmented (8-wide) inclusive scan over j
        float v = lac;
#pragma unroll
        for (int off = 1; off < 8; off <<= 1) {
            float n = __shfl_up(v, off, 64);
            if (j >= off) v += n;
        }
        const float tot = __shfl(v, lane | 7, 64);
        const float att = __expf(-(carry + v - lac) * SCALE);
        carry += tot;

        se0 = fmaf(att, cv[0], se0);
        se1 = fmaf(att, cv[1], se1);
        se2 = fmaf(att, cv[2], se2);
        se3 = fmaf(att, cv[3], se3);
        se4 = fmaf(att, cv[4], se4);

        // rotate pipeline registers (static; compiler renames)
        if (k < 7) {
            cd = cdn;
#pragma unroll
            for (int e = 0; e < 5; ++e) { A[e] = An[e]; B[e] = Bn[e]; }
        }
    }

    // ---- in-group reduce of se over j (segment partials) ----
#pragma unroll
    for (int off = 1; off < 8; off <<= 1) {
        se0 += __shfl_xor(se0, off, 64);
        se1 += __shfl_xor(se1, off, 64);
        se2 += __shfl_xor(se2, off, 64);
        se3 += __shfl_xor(se3, off, 64);
        se4 += __shfl_xor(se4, off, 64);
    }

    if (j == 0) {
        s_seg[w][r][0] = carry;
        s_seg[w][r][1] = se0;
        s_seg[w][r][2] = se1;
        s_seg[w][r][3] = se2;
        s_seg[w][r][4] = se3;
        s_seg[w][r][5] = se4;
    }
    __syncthreads();

    // ---- combine (wave 0): lane = r*8 + seg ----
    if (w == 0) {
        const int seg = j;
        const float Aseg = s_seg[seg][r][0];

        float v = Aseg;
#pragma unroll
        for (int off = 1; off < 8; off <<= 1) {
            float n = __shfl_up(v, off, 64);
            if (seg >= off) v += n;
        }
        const float f = __expf(-(v - Aseg) * SCALE);

        float S0 = f * s_seg[seg][r][1];
        float S1 = f * s_seg[seg][r][2];
        float S2 = f * s_seg[seg][r][3];
        float S3 = f * s_seg[seg][r][4];
        float S4 = f * s_seg[seg][r][5];
#pragma unroll
        for (int off = 1; off < 8; off <<= 1) {
            S0 += __shfl_xor(S0, off, 64);
            S1 += __shfl_xor(S1, off, 64);
            S2 += __shfl_xor(S2, off, 64);
            S3 += __shfl_xor(S3, off, 64);
            S4 += __shfl_xor(S4, off, 64);
        }

        const float rowtot = __shfl(v, lane | 7, 64);
        const size_t b = (size_t)c * 512 + irow0 + r;

        if (seg == 7) {
            out[(size_t)N_LINES * MB_ROWS + b] = rowtot * SCALE;
        }
        {
            const int l = seg;                 // lines 0..7
            const int li = lidx[l];
            float Ssel = S0;
            Ssel = (li == 1) ? S1 : Ssel;
            Ssel = (li == 2) ? S2 : Ssel;
            Ssel = (li == 3) ? S3 : Ssel;
            Ssel = (li == 4) ? S4 : Ssel;
            out[(size_t)l * MB_ROWS + b] = FL_CONST * dfl[l] * Ssel;
        }
        if (seg < 4) {                         // lines 8..11
            const int l = seg + 8;
            const int li = lidx[l];
            float Ssel = S0;
            Ssel = (li == 1) ? S1 : Ssel;
            Ssel = (li == 2) ? S2 : Ssel;
            Ssel = (li == 3) ? S3 : Ssel;
            Ssel = (li == 4) ? S4 : Ssel;
            out[(size_t)l * MB_ROWS + b] = FL_CONST * dfl[l] * Ssel;
        }
    }
}

extern "C" void kernel_launch(void* const* d_in, const int* in_sizes, int n_in,
                              void* d_out, int out_size, void* d_ws, size_t ws_size,
                              hipStream_t stream) {
    const float* xp    = (const float*)d_in[0];
    const float* attCS = (const float*)d_in[1];
    const float* dfl   = (const float*)d_in[2];
    const float* theta = (const float*)d_in[3];
    const int*   lidx  = (const int*)d_in[4];
    float* out = (float*)d_out;

    fused_fl_kernel<<<MB_ROWS / 8, 512, 0, stream>>>(xp, attCS, dfl, theta, lidx, out);
}